// Round 3
// baseline (181.035 us; speedup 1.0000x reference)
//
#include <hip/hip_runtime.h>
#include <math.h>

// Problem constants
constexpr int B_ = 8;
constexpr int N_ = 400;
constexpr int D_ = 768;
constexpr int M_ = 160;                 // int(0.4 * 400)
constexpr int PAIRS_ = M_ * (M_ - 1);   // 25440
constexpr size_t BND_ = (size_t)B_ * N_ * D_;  // 2,457,600

typedef __attribute__((ext_vector_type(8))) short short8;   // 8 bf16 (4 VGPRs)
typedef __attribute__((ext_vector_type(4))) float floatx4;  // MFMA C/D

// Workspace layout (bytes), total ~37.6 MB:
//   z     : double[B_*N_]      @ 0
//   pos   : int[B_*M_]         @ 25600
//   aterm : float[B_*M_*3]     @ 30720   (includes b_pair)
//   bterm : float[B_*M_*3]     @ 46080
//   Xh    : short[BND_]        @ 61440          (bf16 hi of x)
//   Xl    : short[BND_]        @ 4976640        (bf16 lo of x)
//   Yh    : short[3][BND_]     @ 9891840        (bf16 hi of x*w3_c)
//   Yl    : short[3][BND_]     @ 24637440

// ---------------------------------------------------------------------------
// Kernel 1 (prep): one wave per row (all B*N rows; no pos dependency).
//  - z[row] = fp64 dot(x_row, w_span)   (sigmoid monotonic -> rank on z)
//  - Xh/Xl  = bf16 split of x_row
//  - Yh/Yl[c] = bf16 split of x_row * w3[:,c]
__global__ __launch_bounds__(256) void k_prep(const float* __restrict__ x,
                                              const float* __restrict__ w_span,
                                              const float* __restrict__ w_pair,
                                              double* __restrict__ z,
                                              short* __restrict__ Xh,
                                              short* __restrict__ Xl,
                                              short* __restrict__ Yh,
                                              short* __restrict__ Yl) {
  int row = blockIdx.x * 4 + (threadIdx.x >> 6);  // 0..B*N-1
  int lane = threadIdx.x & 63;
  const float* xr = x + (size_t)row * D_;
  const float* w3 = w_pair + 2 * D_ * 3;
  double acc = 0.0;
#pragma unroll
  for (int k = 0; k < D_ / 64; ++k) {
    int d = lane + (k << 6);
    float f = xr[d];
    acc += (double)f * (double)w_span[d];
    size_t o = (size_t)row * D_ + d;
    unsigned hb = __float_as_uint(f) & 0xffff0000u;
    Xh[o] = (short)(hb >> 16);
    Xl[o] = (short)(__float_as_uint(f - __uint_as_float(hb)) >> 16);
#pragma unroll
    for (int c = 0; c < 3; ++c) {
      float y = f * w3[d * 3 + c];
      unsigned yh = __float_as_uint(y) & 0xffff0000u;
      Yh[(size_t)c * BND_ + o] = (short)(yh >> 16);
      Yl[(size_t)c * BND_ + o] = (short)(__float_as_uint(y - __uint_as_float(yh)) >> 16);
    }
  }
#pragma unroll
  for (int off = 32; off > 0; off >>= 1)
    acc += __shfl_down(acc, off, 64);
  if (lane == 0) z[row] = acc;
}

// ---------------------------------------------------------------------------
// Kernel 2 (rank + ab fused): one block per batch.
// Phase 1: pos = sorted ascending of {stable descending rank of z[i] : i<M}.
// Phase 2: aterm[b,i,c] = dot(x_pos[i], w1[:,c]) + b_pair[c];
//          bterm[b,i,c] = dot(x_pos[i], w2[:,c]).
__global__ __launch_bounds__(256) void k_rank_ab(const double* __restrict__ z,
                                                 const float* __restrict__ x,
                                                 const float* __restrict__ w_pair,
                                                 const float* __restrict__ b_pair,
                                                 int* __restrict__ pos,
                                                 float* __restrict__ aterm,
                                                 float* __restrict__ bterm) {
  __shared__ double zsh[N_];
  __shared__ int ranksh[M_];
  __shared__ int possh[M_];
  int b = blockIdx.x;
  int t = threadIdx.x;
  for (int j = t; j < N_; j += 256) zsh[j] = z[b * N_ + j];
  __syncthreads();
  if (t < M_) {
    double zi = zsh[t];
    int cnt = 0;
    for (int j = 0; j < N_; ++j) {
      double zj = zsh[j];
      cnt += (zj > zi) || (zj == zi && j < t);
    }
    ranksh[t] = cnt;
  }
  __syncthreads();
  if (t < M_) {
    int r = ranksh[t];
    int slot = 0;
#pragma unroll 8
    for (int k = 0; k < M_; ++k) slot += (ranksh[k] < r);
    possh[slot] = r;                // ranks are distinct -> ascending sort
    pos[b * M_ + slot] = r;
  }
  __syncthreads();

  int wave = t >> 6, lane = t & 63;
  for (int i = wave; i < M_; i += 4) {
    int row = possh[i];
    const float* xr = x + ((size_t)(b * N_ + row)) * D_;
    float a0 = 0, a1 = 0, a2 = 0, c0 = 0, c1 = 0, c2 = 0;
#pragma unroll 4
    for (int k = 0; k < D_ / 64; ++k) {
      int d = lane + (k << 6);
      float xv = xr[d];
      a0 += xv * w_pair[d * 3 + 0];
      a1 += xv * w_pair[d * 3 + 1];
      a2 += xv * w_pair[d * 3 + 2];
      c0 += xv * w_pair[(D_ + d) * 3 + 0];
      c1 += xv * w_pair[(D_ + d) * 3 + 1];
      c2 += xv * w_pair[(D_ + d) * 3 + 2];
    }
#pragma unroll
    for (int off = 32; off > 0; off >>= 1) {
      a0 += __shfl_down(a0, off, 64);
      a1 += __shfl_down(a1, off, 64);
      a2 += __shfl_down(a2, off, 64);
      c0 += __shfl_down(c0, off, 64);
      c1 += __shfl_down(c1, off, 64);
      c2 += __shfl_down(c2, off, 64);
    }
    if (lane == 0) {
      int wg = b * M_ + i;
      aterm[wg * 3 + 0] = a0 + b_pair[0];
      aterm[wg * 3 + 1] = a1 + b_pair[1];
      aterm[wg * 3 + 2] = a2 + b_pair[2];
      bterm[wg * 3 + 0] = c0;
      bterm[wg * 3 + 1] = c1;
      bterm[wg * 3 + 2] = c2;
    }
  }
}

// ---------------------------------------------------------------------------
// Kernel 3 (MFMA pairs): one wave per (b, 16x16 output tile). Pure bf16
// fragment loads (prepped hi/lo) + 9 MFMA per K=32 step, 3-term split:
// AhiBhi + AhiBlo + AloBhi. Epilogue: +aterm+bterm, sigmoid -> softmax,
// write probs and ranges.
__global__ __launch_bounds__(256) void k_pairs(const short* __restrict__ Xh,
                                               const short* __restrict__ Xl,
                                               const short* __restrict__ Yh,
                                               const short* __restrict__ Yl,
                                               const int* __restrict__ pos,
                                               const float* __restrict__ aterm,
                                               const float* __restrict__ bterm,
                                               const int* __restrict__ span_ranges,
                                               float* __restrict__ out_probs,
                                               float4* __restrict__ out_ranges) {
  int lane = threadIdx.x & 63;
  int w = blockIdx.x * 4 + (threadIdx.x >> 6);  // 0..799
  int b = w / 100;
  int t = w - b * 100;
  int ti = t / 10;            // i-tile (rows of output; A side = Y)
  int tj = t - ti * 10;       // j-tile (cols of output; B side = X)
  int quad = lane >> 4;
  int l16 = lane & 15;

  int i_lane = ti * 16 + l16;
  int j_lane = tj * 16 + l16;
  int pa = pos[b * M_ + i_lane];
  int pb = pos[b * M_ + j_lane];
  size_t oa = ((size_t)(b * N_ + pa)) * D_ + quad * 8;
  size_t ob = ((size_t)(b * N_ + pb)) * D_ + quad * 8;

  const short* ah0 = Yh + 0 * BND_ + oa;
  const short* ah1 = Yh + 1 * BND_ + oa;
  const short* ah2 = Yh + 2 * BND_ + oa;
  const short* al0 = Yl + 0 * BND_ + oa;
  const short* al1 = Yl + 1 * BND_ + oa;
  const short* al2 = Yl + 2 * BND_ + oa;
  const short* bhp = Xh + ob;
  const short* blp = Xl + ob;

  floatx4 acc0 = {0.f, 0.f, 0.f, 0.f};
  floatx4 acc1 = {0.f, 0.f, 0.f, 0.f};
  floatx4 acc2 = {0.f, 0.f, 0.f, 0.f};

#pragma unroll 4
  for (int k = 0; k < D_; k += 32) {
    short8 bh = *(const short8*)(bhp + k);
    short8 bl = *(const short8*)(blp + k);
    short8 h0 = *(const short8*)(ah0 + k);
    short8 l0 = *(const short8*)(al0 + k);
    short8 h1 = *(const short8*)(ah1 + k);
    short8 l1 = *(const short8*)(al1 + k);
    short8 h2 = *(const short8*)(ah2 + k);
    short8 l2 = *(const short8*)(al2 + k);

    acc0 = __builtin_amdgcn_mfma_f32_16x16x32_bf16(h0, bh, acc0, 0, 0, 0);
    acc0 = __builtin_amdgcn_mfma_f32_16x16x32_bf16(h0, bl, acc0, 0, 0, 0);
    acc0 = __builtin_amdgcn_mfma_f32_16x16x32_bf16(l0, bh, acc0, 0, 0, 0);
    acc1 = __builtin_amdgcn_mfma_f32_16x16x32_bf16(h1, bh, acc1, 0, 0, 0);
    acc1 = __builtin_amdgcn_mfma_f32_16x16x32_bf16(h1, bl, acc1, 0, 0, 0);
    acc1 = __builtin_amdgcn_mfma_f32_16x16x32_bf16(l1, bh, acc1, 0, 0, 0);
    acc2 = __builtin_amdgcn_mfma_f32_16x16x32_bf16(h2, bh, acc2, 0, 0, 0);
    acc2 = __builtin_amdgcn_mfma_f32_16x16x32_bf16(h2, bl, acc2, 0, 0, 0);
    acc2 = __builtin_amdgcn_mfma_f32_16x16x32_bf16(l2, bh, acc2, 0, 0, 0);
  }

  // Epilogue. C/D layout: col = lane&15 (j), row = quad*4 + reg (i).
  const float* at = aterm + (size_t)b * M_ * 3;
  const float* bt = bterm + (size_t)b * M_ * 3;
  int j = j_lane;
  float bj0 = bt[j * 3 + 0], bj1 = bt[j * 3 + 1], bj2 = bt[j * 3 + 2];
  int rj0 = span_ranges[pb * 2 + 0], rj1 = span_ranges[pb * 2 + 1];

#pragma unroll
  for (int r = 0; r < 4; ++r) {
    int i = ti * 16 + quad * 4 + r;
    if (i == j) continue;
    float l0 = acc0[r] + at[i * 3 + 0] + bj0;
    float l1 = acc1[r] + at[i * 3 + 1] + bj1;
    float l2 = acc2[r] + at[i * 3 + 2] + bj2;
    float s0 = 1.0f / (1.0f + expf(-l0));
    float s1 = 1.0f / (1.0f + expf(-l1));
    float s2 = 1.0f / (1.0f + expf(-l2));
    float e0 = expf(s0), e1 = expf(s1), e2 = expf(s2);
    float inv = 1.0f / (e0 + e1 + e2);
    int jj = j - (j > i ? 1 : 0);
    size_t p = (size_t)b * PAIRS_ + (size_t)i * (M_ - 1) + jj;
    out_probs[p * 3 + 0] = e0 * inv;
    out_probs[p * 3 + 1] = e1 * inv;
    out_probs[p * 3 + 2] = e2 * inv;
    int pi = pos[b * M_ + i];
    float4 rg;
    rg.x = (float)span_ranges[pi * 2 + 0];
    rg.y = (float)span_ranges[pi * 2 + 1];
    rg.z = (float)rj0;
    rg.w = (float)rj1;
    out_ranges[p] = rg;
  }
}

// ---------------------------------------------------------------------------
extern "C" void kernel_launch(void* const* d_in, const int* in_sizes, int n_in,
                              void* d_out, int out_size, void* d_ws, size_t ws_size,
                              hipStream_t stream) {
  const float* x = (const float*)d_in[0];
  const float* w_span = (const float*)d_in[1];
  // d_in[2] = b_span: constant shift, irrelevant to the ranking -> unused.
  const float* w_pair = (const float*)d_in[3];
  const float* b_pair = (const float*)d_in[4];
  const int* span_ranges = (const int*)d_in[5];

  char* ws = (char*)d_ws;
  double* z = (double*)ws;
  int* pos = (int*)(ws + 25600);
  float* aterm = (float*)(ws + 30720);
  float* bterm = (float*)(ws + 46080);
  short* Xh = (short*)(ws + 61440);
  short* Xl = (short*)(ws + 4976640);
  short* Yh = (short*)(ws + 9891840);
  short* Yl = (short*)(ws + 24637440);

  float* out = (float*)d_out;
  float* out_probs = out;                                         // B*P*3 floats
  float4* out_ranges = (float4*)(out + (size_t)B_ * PAIRS_ * 3);  // B*P*4 floats

  k_prep<<<(B_ * N_) / 4, 256, 0, stream>>>(x, w_span, w_pair, z, Xh, Xl, Yh, Yl);
  k_rank_ab<<<B_, 256, 0, stream>>>(z, x, w_pair, b_pair, pos, aterm, bterm);
  k_pairs<<<(B_ * 100) / 4, 256, 0, stream>>>(Xh, Xl, Yh, Yl, pos, aterm, bterm,
                                              span_ranges, out_probs, out_ranges);
}

// Round 4
// 120.048 us; speedup vs baseline: 1.5080x; 1.5080x over previous
//
#include <hip/hip_runtime.h>
#include <math.h>

// Problem constants
constexpr int B_ = 8;
constexpr int N_ = 400;
constexpr int D_ = 768;
constexpr int M_ = 160;                 // int(0.4 * 400)
constexpr int PAIRS_ = M_ * (M_ - 1);   // 25440
constexpr size_t BND_ = (size_t)B_ * N_ * D_;  // 2,457,600

typedef __attribute__((ext_vector_type(8))) short short8;   // 8 bf16 (4 VGPRs)
typedef __attribute__((ext_vector_type(4))) float floatx4;  // MFMA C/D

// Workspace layout (bytes):
//   z     : double[B_*N_]     @ 0
//   pos   : int[B_*M_]        @ 25600
//   aterm : float[B_*N_*3]    @ 30720    (indexed by raw row; includes b_pair)
//   bterm : float[B_*N_*3]    @ 69120
//   Xh    : short[BND_]       @ 107520        (bf16 hi of x)
//   Xl    : short[BND_]       @ 5022720       (bf16 lo of x)
//   Yh    : short[3][BND_]    @ 9937920       (bf16 hi of x*w3_c)
//   Yl    : short[3][BND_]    @ 24683520

// ---------------------------------------------------------------------------
// Kernel 1 (prep): one wave per row, ALL B*N rows (no pos dependency -> full
// parallelism). Per row:
//   z = fp64 dot(x, w_span)            (sigmoid monotonic -> rank on z)
//   aterm[row,c] = dot(x, w1[:,c]) + b_pair[c];  bterm[row,c] = dot(x, w2[:,c])
//   Xh/Xl = bf16 split of x;  Yh/Yl[c] = bf16 split of x*w3[:,c]
__global__ __launch_bounds__(256) void k_prep(const float* __restrict__ x,
                                              const float* __restrict__ w_span,
                                              const float* __restrict__ w_pair,
                                              const float* __restrict__ b_pair,
                                              double* __restrict__ z,
                                              float* __restrict__ aterm,
                                              float* __restrict__ bterm,
                                              short* __restrict__ Xh,
                                              short* __restrict__ Xl,
                                              short* __restrict__ Yh,
                                              short* __restrict__ Yl) {
  int row = blockIdx.x * 4 + (threadIdx.x >> 6);  // 0..B*N-1
  int lane = threadIdx.x & 63;
  const float* xr = x + (size_t)row * D_;
  const float* w3 = w_pair + 2 * D_ * 3;
  double acc = 0.0;
  float a0 = 0, a1 = 0, a2 = 0, c0 = 0, c1 = 0, c2 = 0;
#pragma unroll
  for (int k = 0; k < D_ / 128; ++k) {  // 2 elements per lane per iter
    int d = (k * 64 + lane) * 2;
    float2 xv = *(const float2*)(xr + d);
    acc += (double)xv.x * (double)w_span[d] + (double)xv.y * (double)w_span[d + 1];
    a0 += xv.x * w_pair[d * 3 + 0] + xv.y * w_pair[(d + 1) * 3 + 0];
    a1 += xv.x * w_pair[d * 3 + 1] + xv.y * w_pair[(d + 1) * 3 + 1];
    a2 += xv.x * w_pair[d * 3 + 2] + xv.y * w_pair[(d + 1) * 3 + 2];
    c0 += xv.x * w_pair[(D_ + d) * 3 + 0] + xv.y * w_pair[(D_ + d + 1) * 3 + 0];
    c1 += xv.x * w_pair[(D_ + d) * 3 + 1] + xv.y * w_pair[(D_ + d + 1) * 3 + 1];
    c2 += xv.x * w_pair[(D_ + d) * 3 + 2] + xv.y * w_pair[(D_ + d + 1) * 3 + 2];

    size_t o = (size_t)row * D_ + d;
    unsigned hx = __float_as_uint(xv.x) & 0xffff0000u;
    unsigned hy = __float_as_uint(xv.y) & 0xffff0000u;
    *(short2*)(Xh + o) = make_short2((short)(hx >> 16), (short)(hy >> 16));
    *(short2*)(Xl + o) =
        make_short2((short)(__float_as_uint(xv.x - __uint_as_float(hx)) >> 16),
                    (short)(__float_as_uint(xv.y - __uint_as_float(hy)) >> 16));
#pragma unroll
    for (int c = 0; c < 3; ++c) {
      float y0 = xv.x * w3[d * 3 + c];
      float y1 = xv.y * w3[(d + 1) * 3 + c];
      unsigned h0 = __float_as_uint(y0) & 0xffff0000u;
      unsigned h1 = __float_as_uint(y1) & 0xffff0000u;
      *(short2*)(Yh + (size_t)c * BND_ + o) =
          make_short2((short)(h0 >> 16), (short)(h1 >> 16));
      *(short2*)(Yl + (size_t)c * BND_ + o) =
          make_short2((short)(__float_as_uint(y0 - __uint_as_float(h0)) >> 16),
                      (short)(__float_as_uint(y1 - __uint_as_float(h1)) >> 16));
    }
  }
#pragma unroll
  for (int off = 32; off > 0; off >>= 1) {
    acc += __shfl_down(acc, off, 64);
    a0 += __shfl_down(a0, off, 64);
    a1 += __shfl_down(a1, off, 64);
    a2 += __shfl_down(a2, off, 64);
    c0 += __shfl_down(c0, off, 64);
    c1 += __shfl_down(c1, off, 64);
    c2 += __shfl_down(c2, off, 64);
  }
  if (lane == 0) {
    z[row] = acc;
    aterm[row * 3 + 0] = a0 + b_pair[0];
    aterm[row * 3 + 1] = a1 + b_pair[1];
    aterm[row * 3 + 2] = a2 + b_pair[2];
    bterm[row * 3 + 0] = c0;
    bterm[row * 3 + 1] = c1;
    bterm[row * 3 + 2] = c2;
  }
}

// ---------------------------------------------------------------------------
// Kernel 2 (rank): per batch, rank[i] (i<M) = stable descending rank of z[i];
// pos = sorted ascending of those ranks. One block per batch (tiny kernel).
__global__ __launch_bounds__(256) void k_rank(const double* __restrict__ z,
                                              int* __restrict__ pos) {
  __shared__ double zsh[N_];
  __shared__ int ranksh[M_];
  int b = blockIdx.x;
  int t = threadIdx.x;
  for (int j = t; j < N_; j += 256) zsh[j] = z[b * N_ + j];
  __syncthreads();
  if (t < M_) {
    double zi = zsh[t];
    int cnt = 0;
    for (int j = 0; j < N_; ++j) {
      double zj = zsh[j];
      cnt += (zj > zi) || (zj == zi && j < t);
    }
    ranksh[t] = cnt;
  }
  __syncthreads();
  if (t < M_) {
    int r = ranksh[t];
    int slot = 0;
#pragma unroll 8
    for (int k = 0; k < M_; ++k) slot += (ranksh[k] < r);
    pos[b * M_ + slot] = r;  // ranks distinct -> ascending sort
  }
}

// ---------------------------------------------------------------------------
// Kernel 3 (MFMA pairs): one wave per (b, 16x16 output tile). Pure bf16
// fragment loads (prepped hi/lo) + 9 MFMA per K=32 step, 3-term split:
// AhiBhi + AhiBlo + AloBhi. Epilogue: +aterm+bterm (indexed by raw row),
// sigmoid -> softmax, write probs and ranges.
__global__ __launch_bounds__(256) void k_pairs(const short* __restrict__ Xh,
                                               const short* __restrict__ Xl,
                                               const short* __restrict__ Yh,
                                               const short* __restrict__ Yl,
                                               const int* __restrict__ pos,
                                               const float* __restrict__ aterm,
                                               const float* __restrict__ bterm,
                                               const int* __restrict__ span_ranges,
                                               float* __restrict__ out_probs,
                                               float4* __restrict__ out_ranges) {
  int lane = threadIdx.x & 63;
  int w = blockIdx.x * 4 + (threadIdx.x >> 6);  // 0..799
  int b = w / 100;
  int t = w - b * 100;
  int ti = t / 10;            // i-tile (rows of output; A side = Y)
  int tj = t - ti * 10;       // j-tile (cols of output; B side = X)
  int quad = lane >> 4;
  int l16 = lane & 15;

  int i_lane = ti * 16 + l16;
  int j_lane = tj * 16 + l16;
  int pa = pos[b * M_ + i_lane];
  int pb = pos[b * M_ + j_lane];
  size_t oa = ((size_t)(b * N_ + pa)) * D_ + quad * 8;
  size_t ob = ((size_t)(b * N_ + pb)) * D_ + quad * 8;

  const short* ah0 = Yh + 0 * BND_ + oa;
  const short* ah1 = Yh + 1 * BND_ + oa;
  const short* ah2 = Yh + 2 * BND_ + oa;
  const short* al0 = Yl + 0 * BND_ + oa;
  const short* al1 = Yl + 1 * BND_ + oa;
  const short* al2 = Yl + 2 * BND_ + oa;
  const short* bhp = Xh + ob;
  const short* blp = Xl + ob;

  floatx4 acc0 = {0.f, 0.f, 0.f, 0.f};
  floatx4 acc1 = {0.f, 0.f, 0.f, 0.f};
  floatx4 acc2 = {0.f, 0.f, 0.f, 0.f};

#pragma unroll 4
  for (int k = 0; k < D_; k += 32) {
    short8 bh = *(const short8*)(bhp + k);
    short8 bl = *(const short8*)(blp + k);
    short8 h0 = *(const short8*)(ah0 + k);
    short8 l0 = *(const short8*)(al0 + k);
    short8 h1 = *(const short8*)(ah1 + k);
    short8 l1 = *(const short8*)(al1 + k);
    short8 h2 = *(const short8*)(ah2 + k);
    short8 l2 = *(const short8*)(al2 + k);

    acc0 = __builtin_amdgcn_mfma_f32_16x16x32_bf16(h0, bh, acc0, 0, 0, 0);
    acc0 = __builtin_amdgcn_mfma_f32_16x16x32_bf16(h0, bl, acc0, 0, 0, 0);
    acc0 = __builtin_amdgcn_mfma_f32_16x16x32_bf16(l0, bh, acc0, 0, 0, 0);
    acc1 = __builtin_amdgcn_mfma_f32_16x16x32_bf16(h1, bh, acc1, 0, 0, 0);
    acc1 = __builtin_amdgcn_mfma_f32_16x16x32_bf16(h1, bl, acc1, 0, 0, 0);
    acc1 = __builtin_amdgcn_mfma_f32_16x16x32_bf16(l1, bh, acc1, 0, 0, 0);
    acc2 = __builtin_amdgcn_mfma_f32_16x16x32_bf16(h2, bh, acc2, 0, 0, 0);
    acc2 = __builtin_amdgcn_mfma_f32_16x16x32_bf16(h2, bl, acc2, 0, 0, 0);
    acc2 = __builtin_amdgcn_mfma_f32_16x16x32_bf16(l2, bh, acc2, 0, 0, 0);
  }

  // Epilogue. C/D layout: col = lane&15 (j), row = quad*4 + reg (i).
  const float* at = aterm + (size_t)b * N_ * 3;
  const float* bt = bterm + (size_t)b * N_ * 3;
  int j = j_lane;
  float bj0 = bt[pb * 3 + 0], bj1 = bt[pb * 3 + 1], bj2 = bt[pb * 3 + 2];
  int rj0 = span_ranges[pb * 2 + 0], rj1 = span_ranges[pb * 2 + 1];

#pragma unroll
  for (int r = 0; r < 4; ++r) {
    int i = ti * 16 + quad * 4 + r;
    if (i == j) continue;
    int pi = pos[b * M_ + i];
    float l0 = acc0[r] + at[pi * 3 + 0] + bj0;
    float l1 = acc1[r] + at[pi * 3 + 1] + bj1;
    float l2 = acc2[r] + at[pi * 3 + 2] + bj2;
    float s0 = 1.0f / (1.0f + expf(-l0));
    float s1 = 1.0f / (1.0f + expf(-l1));
    float s2 = 1.0f / (1.0f + expf(-l2));
    float e0 = expf(s0), e1 = expf(s1), e2 = expf(s2);
    float inv = 1.0f / (e0 + e1 + e2);
    int jj = j - (j > i ? 1 : 0);
    size_t p = (size_t)b * PAIRS_ + (size_t)i * (M_ - 1) + jj;
    out_probs[p * 3 + 0] = e0 * inv;
    out_probs[p * 3 + 1] = e1 * inv;
    out_probs[p * 3 + 2] = e2 * inv;
    float4 rg;
    rg.x = (float)span_ranges[pi * 2 + 0];
    rg.y = (float)span_ranges[pi * 2 + 1];
    rg.z = (float)rj0;
    rg.w = (float)rj1;
    out_ranges[p] = rg;
  }
}

// ---------------------------------------------------------------------------
extern "C" void kernel_launch(void* const* d_in, const int* in_sizes, int n_in,
                              void* d_out, int out_size, void* d_ws, size_t ws_size,
                              hipStream_t stream) {
  const float* x = (const float*)d_in[0];
  const float* w_span = (const float*)d_in[1];
  // d_in[2] = b_span: constant shift, irrelevant to the ranking -> unused.
  const float* w_pair = (const float*)d_in[3];
  const float* b_pair = (const float*)d_in[4];
  const int* span_ranges = (const int*)d_in[5];

  char* ws = (char*)d_ws;
  double* z = (double*)ws;
  int* pos = (int*)(ws + 25600);
  float* aterm = (float*)(ws + 30720);
  float* bterm = (float*)(ws + 69120);
  short* Xh = (short*)(ws + 107520);
  short* Xl = (short*)(ws + 5022720);
  short* Yh = (short*)(ws + 9937920);
  short* Yl = (short*)(ws + 24683520);

  float* out = (float*)d_out;
  float* out_probs = out;                                         // B*P*3 floats
  float4* out_ranges = (float4*)(out + (size_t)B_ * PAIRS_ * 3);  // B*P*4 floats

  k_prep<<<(B_ * N_) / 4, 256, 0, stream>>>(x, w_span, w_pair, b_pair, z,
                                            aterm, bterm, Xh, Xl, Yh, Yl);
  k_rank<<<B_, 256, 0, stream>>>(z, pos);
  k_pairs<<<(B_ * 100) / 4, 256, 0, stream>>>(Xh, Xl, Yh, Yl, pos, aterm, bterm,
                                              span_ranges, out_probs, out_ranges);
}

// Round 5
// 117.771 us; speedup vs baseline: 1.5372x; 1.0193x over previous
//
#include <hip/hip_runtime.h>
#include <math.h>

// Problem constants
constexpr int B_ = 8;
constexpr int N_ = 400;
constexpr int D_ = 768;
constexpr int M_ = 160;                 // int(0.4 * 400)
constexpr int PAIRS_ = M_ * (M_ - 1);   // 25440
constexpr size_t BMD_ = (size_t)B_ * M_ * D_;  // 983,040 (rank-dense)

typedef __attribute__((ext_vector_type(8))) short short8;   // 8 bf16 (4 VGPRs)
typedef __attribute__((ext_vector_type(4))) float floatx4;  // MFMA C/D

// Workspace layout (bytes), total ~15.8 MB, all rank-dense:
//   z     : double[B_*N_]     @ 0
//   pos   : int[B_*M_]        @ 25600
//   aterm : float[B_*M_*3]    @ 30720   (includes b_pair)
//   bterm : float[B_*M_*3]    @ 46080
//   rr    : int[B_*M_*2]      @ 61440   (span_ranges gathered by rank)
//   Xh    : short[BMD_]       @ 71680
//   Xl    : short[BMD_]       @ 2037760
//   Yh    : short[3][BMD_]    @ 4003840
//   Yl    : short[3][BMD_]    @ 9902080

// ---------------------------------------------------------------------------
// Kernel 1: z[row] = fp64 dot(x_row, w_span). One wave per row (all B*N).
// Sigmoid is monotonic -> rank on z.
__global__ __launch_bounds__(256) void k_span(const float* __restrict__ x,
                                              const float* __restrict__ w_span,
                                              double* __restrict__ z) {
  int row = blockIdx.x * 4 + (threadIdx.x >> 6);
  int lane = threadIdx.x & 63;
  const float* xr = x + (size_t)row * D_;
  double acc = 0.0;
#pragma unroll
  for (int it = 0; it < 3; ++it) {
    int d = it * 256 + lane * 4;
    float4 xv = *(const float4*)(xr + d);
    float4 wv = *(const float4*)(w_span + d);
    acc += (double)xv.x * wv.x + (double)xv.y * wv.y +
           (double)xv.z * wv.z + (double)xv.w * wv.w;
  }
#pragma unroll
  for (int off = 32; off > 0; off >>= 1)
    acc += __shfl_down(acc, off, 64);
  if (lane == 0) z[row] = acc;
}

// ---------------------------------------------------------------------------
// Kernel 2: per batch, rank[i] (i<M) = stable descending rank of z[i];
// pos = sorted ascending of those ranks. One block per batch (tiny).
__global__ __launch_bounds__(256) void k_rank(const double* __restrict__ z,
                                              int* __restrict__ pos) {
  __shared__ double zsh[N_];
  __shared__ int ranksh[M_];
  int b = blockIdx.x;
  int t = threadIdx.x;
  for (int j = t; j < N_; j += 256) zsh[j] = z[b * N_ + j];
  __syncthreads();
  if (t < M_) {
    double zi = zsh[t];
    int cnt = 0;
    for (int j = 0; j < N_; ++j) {
      double zj = zsh[j];
      cnt += (zj > zi) || (zj == zi && j < t);
    }
    ranksh[t] = cnt;
  }
  __syncthreads();
  if (t < M_) {
    int r = ranksh[t];
    int slot = 0;
#pragma unroll 8
    for (int k = 0; k < M_; ++k) slot += (ranksh[k] < r);
    pos[b * M_ + slot] = r;  // ranks distinct -> ascending sort
  }
}

// ---------------------------------------------------------------------------
// Kernel 3 (prep, ranked rows only): one wave per rank slot (B*M = 1280).
// Per slot w = b*M+i with source row pos[w]:
//   aterm[w,c] = dot(x, w1[:,c]) + b_pair[c];  bterm[w,c] = dot(x, w2[:,c])
//   Xh/Xl[w]   = bf16 hi/lo split of x;  Yh/Yl[c][w] = split of x*w3[:,c]
//   rr[w]      = span_ranges[pos[w]]
// All global reads/writes coalesced: float4 x, contiguous 12-float w runs,
// short4 split stores, rank-dense destinations.
__global__ __launch_bounds__(256) void k_prep_ranked(const float* __restrict__ x,
                                                     const float* __restrict__ w_pair,
                                                     const float* __restrict__ b_pair,
                                                     const int* __restrict__ pos,
                                                     const int* __restrict__ span_ranges,
                                                     float* __restrict__ aterm,
                                                     float* __restrict__ bterm,
                                                     int* __restrict__ rr,
                                                     short* __restrict__ Xh,
                                                     short* __restrict__ Xl,
                                                     short* __restrict__ Yh,
                                                     short* __restrict__ Yl) {
  int w = blockIdx.x * 4 + (threadIdx.x >> 6);  // rank slot: b*M_ + i
  int lane = threadIdx.x & 63;
  int b = w / M_;
  int row = pos[w];
  const float* xr = x + ((size_t)(b * N_ + row)) * D_;
  const float* w3 = w_pair + 2 * D_ * 3;

  float a0 = 0, a1 = 0, a2 = 0, c0 = 0, c1 = 0, c2 = 0;
#pragma unroll
  for (int it = 0; it < 3; ++it) {
    int d = it * 256 + lane * 4;
    float4 xv = *(const float4*)(xr + d);
    float xf[4] = {xv.x, xv.y, xv.z, xv.w};

    // w1/w2 blocks: rows d..d+3 x 3 ch = 12 consecutive floats each
    float w1v[12], w2v[12], w3v[12];
#pragma unroll
    for (int q = 0; q < 3; ++q) {
      *(float4*)(w1v + 4 * q) = *(const float4*)(w_pair + (size_t)d * 3 + 4 * q);
      *(float4*)(w2v + 4 * q) = *(const float4*)(w_pair + (size_t)(D_ + d) * 3 + 4 * q);
      *(float4*)(w3v + 4 * q) = *(const float4*)(w3 + (size_t)d * 3 + 4 * q);
    }
#pragma unroll
    for (int e = 0; e < 4; ++e) {
      a0 += xf[e] * w1v[e * 3 + 0];
      a1 += xf[e] * w1v[e * 3 + 1];
      a2 += xf[e] * w1v[e * 3 + 2];
      c0 += xf[e] * w2v[e * 3 + 0];
      c1 += xf[e] * w2v[e * 3 + 1];
      c2 += xf[e] * w2v[e * 3 + 2];
    }

    size_t o = (size_t)w * D_ + d;
    short xh[4], xl[4];
#pragma unroll
    for (int e = 0; e < 4; ++e) {
      unsigned h = __float_as_uint(xf[e]) & 0xffff0000u;
      xh[e] = (short)(h >> 16);
      xl[e] = (short)(__float_as_uint(xf[e] - __uint_as_float(h)) >> 16);
    }
    *(short4*)(Xh + o) = make_short4(xh[0], xh[1], xh[2], xh[3]);
    *(short4*)(Xl + o) = make_short4(xl[0], xl[1], xl[2], xl[3]);
#pragma unroll
    for (int c = 0; c < 3; ++c) {
      short yh[4], yl[4];
#pragma unroll
      for (int e = 0; e < 4; ++e) {
        float y = xf[e] * w3v[e * 3 + c];
        unsigned h = __float_as_uint(y) & 0xffff0000u;
        yh[e] = (short)(h >> 16);
        yl[e] = (short)(__float_as_uint(y - __uint_as_float(h)) >> 16);
      }
      *(short4*)(Yh + (size_t)c * BMD_ + o) = make_short4(yh[0], yh[1], yh[2], yh[3]);
      *(short4*)(Yl + (size_t)c * BMD_ + o) = make_short4(yl[0], yl[1], yl[2], yl[3]);
    }
  }
#pragma unroll
  for (int off = 32; off > 0; off >>= 1) {
    a0 += __shfl_down(a0, off, 64);
    a1 += __shfl_down(a1, off, 64);
    a2 += __shfl_down(a2, off, 64);
    c0 += __shfl_down(c0, off, 64);
    c1 += __shfl_down(c1, off, 64);
    c2 += __shfl_down(c2, off, 64);
  }
  if (lane == 0) {
    aterm[w * 3 + 0] = a0 + b_pair[0];
    aterm[w * 3 + 1] = a1 + b_pair[1];
    aterm[w * 3 + 2] = a2 + b_pair[2];
    bterm[w * 3 + 0] = c0;
    bterm[w * 3 + 1] = c1;
    bterm[w * 3 + 2] = c2;
    *(int2*)(rr + w * 2) = *(const int2*)(span_ranges + row * 2);
  }
}

// ---------------------------------------------------------------------------
// Kernel 4 (MFMA pairs): one wave per (b, 16x16 tile). All inputs rank-dense:
// pure short8 fragment loads + 9 MFMA per K=32 step (3-term bf16 split:
// AhiBhi + AhiBlo + AloBhi). Epilogue: +aterm+bterm, sigmoid -> softmax,
// write probs and ranges.
__global__ __launch_bounds__(256) void k_pairs(const short* __restrict__ Xh,
                                               const short* __restrict__ Xl,
                                               const short* __restrict__ Yh,
                                               const short* __restrict__ Yl,
                                               const float* __restrict__ aterm,
                                               const float* __restrict__ bterm,
                                               const int* __restrict__ rr,
                                               float* __restrict__ out_probs,
                                               float4* __restrict__ out_ranges) {
  int lane = threadIdx.x & 63;
  int w = blockIdx.x * 4 + (threadIdx.x >> 6);  // 0..799
  int b = w / 100;
  int t = w - b * 100;
  int ti = t / 10;            // i-tile (rows; A side = Y)
  int tj = t - ti * 10;       // j-tile (cols; B side = X)
  int quad = lane >> 4;
  int l16 = lane & 15;

  size_t oa = ((size_t)(b * M_ + ti * 16 + l16)) * D_ + quad * 8;
  size_t ob = ((size_t)(b * M_ + tj * 16 + l16)) * D_ + quad * 8;

  const short* ah0 = Yh + 0 * BMD_ + oa;
  const short* ah1 = Yh + 1 * BMD_ + oa;
  const short* ah2 = Yh + 2 * BMD_ + oa;
  const short* al0 = Yl + 0 * BMD_ + oa;
  const short* al1 = Yl + 1 * BMD_ + oa;
  const short* al2 = Yl + 2 * BMD_ + oa;
  const short* bhp = Xh + ob;
  const short* blp = Xl + ob;

  floatx4 acc0 = {0.f, 0.f, 0.f, 0.f};
  floatx4 acc1 = {0.f, 0.f, 0.f, 0.f};
  floatx4 acc2 = {0.f, 0.f, 0.f, 0.f};

#pragma unroll 4
  for (int k = 0; k < D_; k += 32) {
    short8 bh = *(const short8*)(bhp + k);
    short8 bl = *(const short8*)(blp + k);
    short8 h0 = *(const short8*)(ah0 + k);
    short8 l0 = *(const short8*)(al0 + k);
    short8 h1 = *(const short8*)(ah1 + k);
    short8 l1 = *(const short8*)(al1 + k);
    short8 h2 = *(const short8*)(ah2 + k);
    short8 l2 = *(const short8*)(al2 + k);

    acc0 = __builtin_amdgcn_mfma_f32_16x16x32_bf16(h0, bh, acc0, 0, 0, 0);
    acc0 = __builtin_amdgcn_mfma_f32_16x16x32_bf16(h0, bl, acc0, 0, 0, 0);
    acc0 = __builtin_amdgcn_mfma_f32_16x16x32_bf16(l0, bh, acc0, 0, 0, 0);
    acc1 = __builtin_amdgcn_mfma_f32_16x16x32_bf16(h1, bh, acc1, 0, 0, 0);
    acc1 = __builtin_amdgcn_mfma_f32_16x16x32_bf16(h1, bl, acc1, 0, 0, 0);
    acc1 = __builtin_amdgcn_mfma_f32_16x16x32_bf16(l1, bh, acc1, 0, 0, 0);
    acc2 = __builtin_amdgcn_mfma_f32_16x16x32_bf16(h2, bh, acc2, 0, 0, 0);
    acc2 = __builtin_amdgcn_mfma_f32_16x16x32_bf16(h2, bl, acc2, 0, 0, 0);
    acc2 = __builtin_amdgcn_mfma_f32_16x16x32_bf16(l2, bh, acc2, 0, 0, 0);
  }

  // Epilogue. C/D layout: col = lane&15 (j), row = quad*4 + reg (i).
  const float* at = aterm + (size_t)(b * M_) * 3;
  const float* bt = bterm + (size_t)(b * M_) * 3;
  const int* rrb = rr + (size_t)(b * M_) * 2;
  int j = tj * 16 + l16;
  float bj0 = bt[j * 3 + 0], bj1 = bt[j * 3 + 1], bj2 = bt[j * 3 + 2];
  int rj0 = rrb[j * 2 + 0], rj1 = rrb[j * 2 + 1];

#pragma unroll
  for (int r = 0; r < 4; ++r) {
    int i = ti * 16 + quad * 4 + r;
    if (i == j) continue;
    float l0 = acc0[r] + at[i * 3 + 0] + bj0;
    float l1 = acc1[r] + at[i * 3 + 1] + bj1;
    float l2 = acc2[r] + at[i * 3 + 2] + bj2;
    float s0 = 1.0f / (1.0f + expf(-l0));
    float s1 = 1.0f / (1.0f + expf(-l1));
    float s2 = 1.0f / (1.0f + expf(-l2));
    float e0 = expf(s0), e1 = expf(s1), e2 = expf(s2);
    float inv = 1.0f / (e0 + e1 + e2);
    int jj = j - (j > i ? 1 : 0);
    size_t p = (size_t)b * PAIRS_ + (size_t)i * (M_ - 1) + jj;
    out_probs[p * 3 + 0] = e0 * inv;
    out_probs[p * 3 + 1] = e1 * inv;
    out_probs[p * 3 + 2] = e2 * inv;
    float4 rg;
    rg.x = (float)rrb[i * 2 + 0];
    rg.y = (float)rrb[i * 2 + 1];
    rg.z = (float)rj0;
    rg.w = (float)rj1;
    out_ranges[p] = rg;
  }
}

// ---------------------------------------------------------------------------
extern "C" void kernel_launch(void* const* d_in, const int* in_sizes, int n_in,
                              void* d_out, int out_size, void* d_ws, size_t ws_size,
                              hipStream_t stream) {
  const float* x = (const float*)d_in[0];
  const float* w_span = (const float*)d_in[1];
  // d_in[2] = b_span: constant shift, irrelevant to the ranking -> unused.
  const float* w_pair = (const float*)d_in[3];
  const float* b_pair = (const float*)d_in[4];
  const int* span_ranges = (const int*)d_in[5];

  char* ws = (char*)d_ws;
  double* z = (double*)ws;
  int* pos = (int*)(ws + 25600);
  float* aterm = (float*)(ws + 30720);
  float* bterm = (float*)(ws + 46080);
  int* rr = (int*)(ws + 61440);
  short* Xh = (short*)(ws + 71680);
  short* Xl = (short*)(ws + 2037760);
  short* Yh = (short*)(ws + 4003840);
  short* Yl = (short*)(ws + 9902080);

  float* out = (float*)d_out;
  float* out_probs = out;                                         // B*P*3 floats
  float4* out_ranges = (float4*)(out + (size_t)B_ * PAIRS_ * 3);  // B*P*4 floats

  k_span<<<(B_ * N_) / 4, 256, 0, stream>>>(x, w_span, z);
  k_rank<<<B_, 256, 0, stream>>>(z, pos);
  k_prep_ranked<<<(B_ * M_) / 4, 256, 0, stream>>>(x, w_pair, b_pair, pos,
                                                   span_ranges, aterm, bterm,
                                                   rr, Xh, Xl, Yh, Yl);
  k_pairs<<<(B_ * 100) / 4, 256, 0, stream>>>(Xh, Xl, Yh, Yl, aterm, bterm, rr,
                                              out_probs, out_ranges);
}